// Round 10
// baseline (281.365 us; speedup 1.0000x reference)
//
#include <hip/hip_runtime.h>
#include <hip/hip_bf16.h>

// Established facts (R1..R9 on HW):
//  - Harness I/O FP32. Timed window includes harness reset: 536MB d_ws 0xAA fill
//    (77us @87% HBM) + x restore (~39us) => ~120us fixed floor. Our kernels ~125us.
//  - MFMA 16x16x32_bf16 layouts verified in-harness (R6..R9):
//      A[m=lane&15][k=(lane>>4)*8+j], B[n=lane&15][k=(lane>>4)*8+j],
//      C/D col=lane&15, row=(lane>>4)*4+reg.
//  - R9: persistent branch-blocks + B-in-registers beat the 98us plateau (->~63us).
//    Residual = block-wide barrier drains at 1 block/CU. This round: 3 barriers/graph
//    (separate h/partial buffers), 2 blocks/CU, parallel glist build.

#define G_   4096
#define NPG_ 32
#define NN_  (G_*NPG_)     // 131072
#define D_   256
#define SH_  256
#define HDG_ 50
#define HDN_ 3

// output layout (fp32 elements): g_head | n_head | g_var | n_var
#define OFF_GH 0
#define OFF_NH (G_*HDG_)             // 204800
#define OFF_GV (OFF_NH + NN_*HDN_)   // 598016
#define OFF_NV (OFF_GV + G_*HDG_)    // 802816

typedef short v8s __attribute__((ext_vector_type(8)));   // 8 bf16 = 16 B (MFMA A/B frag)
typedef short v4s __attribute__((ext_vector_type(4)));
typedef float v4f __attribute__((ext_vector_type(4)));   // MFMA C/D frag

__device__ __forceinline__ float bfu2f(unsigned short u) {
    return __uint_as_float(((unsigned int)u) << 16);
}
__device__ __forceinline__ unsigned short f2bfu(float v) {
    __hip_bfloat16 b = __float2bfloat16(v);
    return *reinterpret_cast<unsigned short*>(&b);
}

#define MFMA16(a, b, c) __builtin_amdgcn_mfma_f32_16x16x32_bf16((a), (b), (c), 0, 0, 0)

// ---- weight packing (fp32 -> bf16, B-fragment layouts) + gcnt zeroing ----
__global__ __launch_bounds__(256) void wpack(const float* __restrict__ Wn1,
                                             const float* __restrict__ Wgs,
                                             const float* __restrict__ Wgh,
                                             const float* __restrict__ Wn2,
                                             unsigned short* __restrict__ out,
                                             int* __restrict__ gcnt) {
    if (blockIdx.x == 0 && threadIdx.x < 2) gcnt[threadIdx.x] = 0;
    const int idx = blockIdx.x * 256 + threadIdx.x;   // 0 .. 335871
    float v;
    if (idx < 131072) {
        const int b = idx >> 16, rem = idx & 65535, s = rem >> 8, d = rem & 255;
        v = Wn1[b * 65536 + d * 256 + s];
    } else if (idx < 262144) {
        const int i2 = idx - 131072;
        const int np = i2 >> 8, d = i2 & 255;
        v = Wgs[(np >> 8) * 65536 + d * 256 + (np & 255)];
    } else if (idx < 327680) {
        const int i3 = idx - 262144;
        const int npp = i3 >> 8, k = i3 & 255;
        const int b = npp >> 7, c = npp & 127;
        v = (c < 100) ? Wgh[b * 25600 + k * 100 + c] : 0.f;
    } else {
        const int i4 = idx - 327680;
        const int b = i4 >> 12, rem = i4 & 4095, n = rem >> 8, k = rem & 255;
        v = (n < 6) ? Wn2[b * 1536 + k * 6 + n] : 0.f;
    }
    out[idx] = f2bfu(v);
}

// ---- per-branch graph lists, 16 blocks (order irrelevant; device-scope atomics) ----
__global__ __launch_bounds__(256) void build_glist16(const int* __restrict__ dsname,
                                                     int* __restrict__ glist,    // [2][4096]
                                                     int* __restrict__ gcnt) {   // [2]
    const int g = blockIdx.x * 256 + threadIdx.x;
    const int b = dsname[g];
    const int slot = atomicAdd(&gcnt[b], 1);
    glist[b * G_ + slot] = g;
}

// ---- persistent node kernel: 512 blocks x 512 threads (2 blocks/CU).
// block branch = blockIdx&1; ~8 graphs each. L1 B-frags in registers (64 VGPR).
// 3 barriers/graph: A (stage+mean visible), C (h complete), D (L2 partials). ----
__global__ __launch_bounds__(512, 4) void node_pers2(const float* __restrict__ x,
                                                     const int* __restrict__ glist,
                                                     const int* __restrict__ gcnt,
                                                     const unsigned short* __restrict__ Wn1T,
                                                     const float* __restrict__ bn1,
                                                     const unsigned short* __restrict__ Wn2b,
                                                     const float* __restrict__ bn2,
                                                     unsigned short* __restrict__ xg,
                                                     float* __restrict__ out) {
    __shared__ __align__(16) unsigned short xs[NPG_ * 264];    // 16.9 KB bf16 x-tile
    __shared__ __align__(16) unsigned short hb[NPG_ * 264];    // 16.9 KB bf16 h
    __shared__ __align__(16) float red[8 * 256];               // 8 KB mean partials
    __shared__ __align__(16) float red2[4 * 512];              // 8 KB L2 partials
    const int t = threadIdx.x;
    const int wave = t >> 6, lane = t & 63;
    const int l15 = lane & 15, quad = lane >> 4;
    const int br = blockIdx.x & 1;
    const int bslot = blockIdx.x >> 1;        // 0..255
    const int cnt = gcnt[br];

    // wave's hidden columns: base_n + nt*16 + l15 (nt<2); union over 8 waves = 0..255
    const int base_n = (wave & 1) * 128 + (wave >> 1) * 32;

    // L1 B fragments + bias: loaded ONCE per block
    v8s B1[2][8];
    float bias1[2];
    #pragma unroll
    for (int nt = 0; nt < 2; nt++) {
        const unsigned short* bp = Wn1T + br * 65536 + (base_n + nt * 16 + l15) * 256 + quad * 8;
        #pragma unroll
        for (int kt = 0; kt < 8; kt++) B1[nt][kt] = *(const v8s*)(bp + kt * 32);
        bias1[nt] = bn1[br * 256 + base_n + nt * 16 + l15];
    }

    // L2 B fragments: wave = (kh=w>>1 in 0..3 -> K=64 slice, mtl=w&1). 2 frags/wave.
    const int kh = wave >> 1, mtl = wave & 1;
    v8s B2[2];
    {
        const unsigned short* bp = Wn2b + br * 4096 + l15 * 256 + kh * 64 + quad * 8;
        B2[0] = *(const v8s*)(bp);
        B2[1] = *(const v8s*)(bp + 32);
    }
    float bias2 = 0.f; int i2 = 0, c2 = 0;
    if (t < 192) { i2 = t / 6; c2 = t % 6; bias2 = bn2[br * 6 + c2]; }

    const int rb = t >> 6;            // 0..7: rows rb*4..rb*4+3
    const int colb = (t & 63) * 4;    // 16-B coalesced columns

    // prefetch first graph
    int gi = bslot;
    int g = glist[br * G_ + ((gi < cnt) ? gi : (cnt > 0 ? cnt - 1 : 0))];
    float4 pv[4];
    #pragma unroll
    for (int k = 0; k < 4; k++)
        pv[k] = *(const float4*)(x + (size_t)g * 8192 + (rb * 4 + k) * 256 + colb);

    for (; gi < cnt; gi += 256) {
        const int gcur = g;
        // convert pv -> xs (bf16) + fp32 mean partials
        float s0 = 0.f, s1 = 0.f, s2 = 0.f, s3 = 0.f;
        #pragma unroll
        for (int k = 0; k < 4; k++) {
            s0 += pv[k].x; s1 += pv[k].y; s2 += pv[k].z; s3 += pv[k].w;
            v4s bv; bv[0] = (short)f2bfu(pv[k].x); bv[1] = (short)f2bfu(pv[k].y);
                    bv[2] = (short)f2bfu(pv[k].z); bv[3] = (short)f2bfu(pv[k].w);
            *(v4s*)(&xs[(rb * 4 + k) * 264 + colb]) = bv;
        }
        *(float4*)(&red[rb * 256 + colb]) = make_float4(s0, s1, s2, s3);

        // prefetch NEXT graph (hidden under MFMA phase)
        {
            const int gi2 = gi + 256;
            const int gn = glist[br * G_ + ((gi2 < cnt) ? gi2 : (cnt - 1))];
            #pragma unroll
            for (int k = 0; k < 4; k++)
                pv[k] = *(const float4*)(x + (size_t)gn * 8192 + (rb * 4 + k) * 256 + colb);
            g = gn;
        }
        __syncthreads();   // A: xs + mean partials visible

        // mean -> xg (reads complete before this thread's barrier C)
        if (t < 256) {
            float m = 0.f;
            #pragma unroll
            for (int r = 0; r < 8; r++) m += red[r * 256 + t];
            xg[(size_t)gcur * 256 + t] = f2bfu(m * (1.0f / NPG_));
        }

        // L1 MFMA: M=32, wave's N=32, K=256; B from registers
        v4f acc[2][2];
        #pragma unroll
        for (int mt = 0; mt < 2; mt++)
            #pragma unroll
            for (int nt = 0; nt < 2; nt++) acc[mt][nt] = (v4f){0.f, 0.f, 0.f, 0.f};
        #pragma unroll
        for (int kt = 0; kt < 8; kt++) {
            const int ko = kt * 32;
            v8s a0 = *(const v8s*)(&xs[l15 * 264 + quad * 8 + ko]);
            v8s a1 = *(const v8s*)(&xs[(16 + l15) * 264 + quad * 8 + ko]);
            #pragma unroll
            for (int nt = 0; nt < 2; nt++) {
                acc[0][nt] = MFMA16(a0, B1[nt][kt], acc[0][nt]);
                acc[1][nt] = MFMA16(a1, B1[nt][kt], acc[1][nt]);
            }
        }

        // bias + ReLU -> h (bf16) into hb (own columns; no barrier needed before)
        #pragma unroll
        for (int nt = 0; nt < 2; nt++) {
            const int col = base_n + nt * 16 + l15;
            #pragma unroll
            for (int mt = 0; mt < 2; mt++)
                #pragma unroll
                for (int r = 0; r < 4; r++) {
                    const int row = mt * 16 + quad * 4 + r;
                    const float v = acc[mt][nt][r] + bias1[nt];
                    hb[row * 264 + col] = f2bfu(v > 0.f ? v : 0.f);
                }
        }
        __syncthreads();   // C: h complete

        // L2 MFMA: all 8 waves; M=16 (mtl), N=16 (6 valid), K=64 (kh); partials -> red2
        {
            v4f a2 = (v4f){0.f, 0.f, 0.f, 0.f};
            const int kb = kh * 64 + quad * 8;
            v8s av0 = *(const v8s*)(&hb[(mtl * 16 + l15) * 264 + kb]);
            v8s av1 = *(const v8s*)(&hb[(mtl * 16 + l15) * 264 + kb + 32]);
            a2 = MFMA16(av0, B2[0], a2);
            a2 = MFMA16(av1, B2[1], a2);
            #pragma unroll
            for (int r = 0; r < 4; r++)
                red2[kh * 512 + (mtl * 16 + quad * 4 + r) * 16 + l15] = a2[r];
        }
        __syncthreads();   // D: partials visible

        if (t < 192) {
            const float o = red2[i2 * 16 + c2] + red2[512 + i2 * 16 + c2]
                          + red2[1024 + i2 * 16 + c2] + red2[1536 + i2 * 16 + c2] + bias2;
            const int n = gcur * NPG_ + i2;
            if (c2 < HDN_) out[OFF_NH + n * HDN_ + c2] = o;
            else           out[OFF_NV + n * HDN_ + (c2 - HDN_)] = o * o;
        }
        // no barrier E: red2 rewritten only after next iteration's barrier A;
        // xs rewritten only after this thread's epilogue (thread-local order);
        // all cross-thread hazards separated by A/C/D of the next iteration.
    }
}

// ---- graph MLP, all-MFMA — R7-verbatim (proven) ----
__global__ __launch_bounds__(256) void graph_mfma2(const unsigned short* __restrict__ xg,
                                                   const int* __restrict__ dsname,
                                                   const unsigned short* __restrict__ WgsT,
                                                   const float* __restrict__ bgs,
                                                   const unsigned short* __restrict__ WghP,
                                                   const float* __restrict__ bgh,
                                                   float* __restrict__ out) {
    __shared__ __align__(16) unsigned short xs[32 * 264];
    __shared__ int bls[32];
    const int gbase = blockIdx.x * 32;
    const int t = threadIdx.x;
    const int wave = t >> 6, lane = t & 63;
    const int l15 = lane & 15, quad = lane >> 4;
    if (t < 32) bls[t] = dsname[gbase + t];

    #pragma unroll
    for (int k = 0; k < 4; k++) {
        const int flat = k * 2048 + t * 8;
        *(v8s*)(&xs[(flat >> 8) * 264 + (flat & 255)]) =
            *(const v8s*)(xg + (size_t)gbase * 256 + flat);
    }
    __syncthreads();

    v4f acc[2][8];
    #pragma unroll
    for (int mt = 0; mt < 2; mt++)
        #pragma unroll
        for (int nt = 0; nt < 8; nt++) acc[mt][nt] = (v4f){0.f, 0.f, 0.f, 0.f};

    const unsigned short* Ab = &xs[l15 * 264 + quad * 8];
    const unsigned short* Bb = WgsT + (wave * 128 + l15) * 256 + quad * 8;

    #pragma unroll
    for (int kt = 0; kt < 8; kt++) {
        const int ko = kt * 32;
        v8s a0 = *(const v8s*)(Ab + ko);
        v8s a1 = *(const v8s*)(Ab + 16 * 264 + ko);
        #pragma unroll
        for (int nt = 0; nt < 8; nt++) {
            v8s bv = *(const v8s*)(Bb + nt * 16 * 256 + ko);
            acc[0][nt] = MFMA16(a0, bv, acc[0][nt]);
            acc[1][nt] = MFMA16(a1, bv, acc[1][nt]);
        }
    }
    __syncthreads();

    {
        const int bw = wave >> 1;
        #pragma unroll
        for (int nt = 0; nt < 8; nt++) {
            const int sp = wave * 128 + nt * 16 + l15;
            const int s_local = sp & 255;
            const float bias = bgs[sp];
            #pragma unroll
            for (int mt = 0; mt < 2; mt++)
                #pragma unroll
                for (int r = 0; r < 4; r++) {
                    const int row = mt * 16 + quad * 4 + r;
                    if (bls[row] == bw) {
                        const float v = acc[mt][nt][r] + bias;
                        xs[row * 264 + s_local] = f2bfu(v > 0.f ? v : 0.f);
                    }
                }
        }
    }
    __syncthreads();

    v4f acc2[2][4];
    #pragma unroll
    for (int mt = 0; mt < 2; mt++)
        #pragma unroll
        for (int nt = 0; nt < 4; nt++) acc2[mt][nt] = (v4f){0.f, 0.f, 0.f, 0.f};

    const unsigned short* B2 = WghP + ((wave * 4) * 16 + l15) * 256 + quad * 8;
    #pragma unroll
    for (int kt = 0; kt < 8; kt++) {
        const int ko = kt * 32;
        v8s a0 = *(const v8s*)(&xs[l15 * 264 + ko + quad * 8]);
        v8s a1 = *(const v8s*)(&xs[(16 + l15) * 264 + ko + quad * 8]);
        #pragma unroll
        for (int nt = 0; nt < 4; nt++) {
            v8s bv = *(const v8s*)(B2 + nt * 16 * 256 + ko);
            acc2[0][nt] = MFMA16(a0, bv, acc2[0][nt]);
            acc2[1][nt] = MFMA16(a1, bv, acc2[1][nt]);
        }
    }

    #pragma unroll
    for (int nt = 0; nt < 4; nt++) {
        const int npp  = (wave * 4 + nt) * 16 + l15;
        const int bo   = npp >> 7, c = npp & 127;
        if (c < 2 * HDG_) {
            const float bias = bgh[bo * 2 * HDG_ + c];
            #pragma unroll
            for (int mt = 0; mt < 2; mt++)
                #pragma unroll
                for (int r = 0; r < 4; r++) {
                    const int row = mt * 16 + quad * 4 + r;
                    if (bls[row] == bo) {
                        const float o = acc2[mt][nt][r] + bias;
                        const int g = gbase + row;
                        if (c < HDG_) out[OFF_GH + g * HDG_ + c] = o;
                        else          out[OFF_GV + g * HDG_ + (c - HDG_)] = o * o;
                    }
                }
        }
    }
}

extern "C" void kernel_launch(void* const* d_in, const int* in_sizes, int n_in,
                              void* d_out, int out_size, void* d_ws, size_t ws_size,
                              hipStream_t stream) {
    const float* x      = (const float*)d_in[0];
    const int*   dsname = (const int*)d_in[1];
    // d_in[2] = batch: arange(N)//32 by construction; structure used directly.
    const float* Wgs = (const float*)d_in[3];
    const float* bgs = (const float*)d_in[4];
    const float* Wgh = (const float*)d_in[5];
    const float* bgh = (const float*)d_in[6];
    const float* Wn1 = (const float*)d_in[7];
    const float* bn1 = (const float*)d_in[8];
    const float* Wn2 = (const float*)d_in[9];
    const float* bn2 = (const float*)d_in[10];
    float* out = (float*)d_out;

    unsigned short* wsbuf = (unsigned short*)d_ws;
    unsigned short* Wn1T  = wsbuf;              // @0        (131072 u16)
    unsigned short* WgsT  = wsbuf + 131072;     // @262144B  (131072)
    unsigned short* WghP  = wsbuf + 262144;     // @524288B  (65536)
    unsigned short* Wn2b  = wsbuf + 327680;     // @655360B  (8192)
    unsigned short* xg    = wsbuf + 335872;     // @671744B  (1048576 u16, 2MB)
    int* glist = (int*)((char*)d_ws + 2768896); // 2*4096 ints
    int* gcnt  = (int*)((char*)d_ws + 2801664); // 2 ints

    wpack        <<<1312,    256, 0, stream>>>(Wn1, Wgs, Wgh, Wn2, wsbuf, gcnt);
    build_glist16<<<16,      256, 0, stream>>>(dsname, glist, gcnt);
    node_pers2   <<<512,     512, 0, stream>>>(x, glist, gcnt, Wn1T, bn1, Wn2b, bn2, xg, out);
    graph_mfma2  <<<G_ / 32, 256, 0, stream>>>(xg, dsname, WgsT, bgs, WghP, bgh, out);
}